// Round 1
// baseline (776.974 us; speedup 1.0000x reference)
//
#include <hip/hip_runtime.h>

#define IMH 480
#define IMW 640
#define HW (IMH*IMW)
#define NB 16

// ---- order-preserving float<->uint encoding (for atomic min/max) ----
__device__ inline unsigned fenc(float x){
    unsigned u = __float_as_uint(x);
    return (u & 0x80000000u) ? ~u : (u | 0x80000000u);
}
__device__ inline float fdec(unsigned e){
    unsigned u = (e & 0x80000000u) ? (e & 0x7FFFFFFFu) : ~e;
    return __uint_as_float(u);
}

// ---- weights = 1.0 ----
__global__ __launch_bounds__(256) void fill_weights(float* __restrict__ w){
    int i = blockIdx.x*256 + threadIdx.x;
    if (i < NB*HW/4) ((float4*)w)[i] = make_float4(1.f,1.f,1.f,1.f);
}

// ---- init: copy R,t to state, zero accumulators, init min/max ----
__global__ void init_kernel(const float* __restrict__ Rin, const float* __restrict__ tin,
                            float* __restrict__ stateR, float* __restrict__ statet,
                            unsigned* __restrict__ mm, float* __restrict__ acc){
    int i = threadIdx.x;
    if (i < NB*9) stateR[i] = Rin[i];
    if (i < NB*3) statet[i] = tin[i];
    if (i == 0){ mm[0] = 0xFFFFFFFFu; mm[1] = 0u; }
    for (int k = i; k < NB*27; k += 256) acc[k] = 0.f;
}

// ---- global min/max of depth1 ----
__global__ __launch_bounds__(256) void minmax_kernel(const float* __restrict__ d, unsigned* __restrict__ mm){
    unsigned lmin = 0xFFFFFFFFu, lmax = 0u;
    const int total = NB*HW;
    for (int i = blockIdx.x*256 + threadIdx.x; i < total; i += gridDim.x*256){
        unsigned e = fenc(d[i]);
        lmin = min(lmin, e); lmax = max(lmax, e);
    }
    #pragma unroll
    for (int off = 32; off; off >>= 1){
        lmin = min(lmin, (unsigned)__shfl_down((int)lmin, off));
        lmax = max(lmax, (unsigned)__shfl_down((int)lmax, off));
    }
    if ((threadIdx.x & 63) == 0){ atomicMin(&mm[0], lmin); atomicMax(&mm[1], lmax); }
}

// ---- normal1: sobel over vertex1 (recomputed from depth1), cross, normalize, mask ----
__global__ __launch_bounds__(256) void normal_kernel(const float* __restrict__ depth1,
                                                     const float* __restrict__ Kp,
                                                     const unsigned* __restrict__ mm,
                                                     float* __restrict__ normal1){
    int b = blockIdx.y;
    int pix = blockIdx.x*256 + threadIdx.x;
    int r = pix / IMW, c = pix % IMW;
    const float fx = Kp[b*4+0], fy = Kp[b*4+1], cx = Kp[b*4+2], cy = Kp[b*4+3];
    const float* __restrict__ d = depth1 + (size_t)b*HW;
    int rm = max(r-1,0), rp = min(r+1,IMH-1), cm = max(c-1,0), cp = min(c+1,IMW-1);

    auto vert = [&](int rr, int cc, float v[3]){
        float dd = d[rr*IMW+cc];
        v[0] = ((float)cc - cx)/fx*dd;
        v[1] = ((float)rr - cy)/fy*dd;
        v[2] = dd;
    };
    float va[3],vb[3],vc2[3],vd[3],ve[3],vf[3],vg[3],vh[3];
    vert(rm,cm,va); vert(rm,c,vb);  vert(rm,cp,vc2);
    vert(r ,cm,vd);                 vert(r ,cp,ve);
    vert(rp,cm,vf); vert(rp,c,vg);  vert(rp,cp,vh);

    float dx[3], dy[3];
    #pragma unroll
    for (int k=0;k<3;k++){
        dx[k] = (vc2[k]-va[k]) + 2.f*(ve[k]-vd[k]) + (vh[k]-vf[k]);
        dy[k] = (vf[k]-va[k]) + 2.f*(vg[k]-vb[k]) + (vh[k]-vc2[k]);
    }
    float nx = dx[1]*dy[2] - dx[2]*dy[1];
    float ny = dx[2]*dy[0] - dx[0]*dy[2];
    float nz = dx[0]*dy[1] - dx[1]*dy[0];
    float mag = sqrtf(nx*nx + ny*ny + nz*nz + 1e-16f);
    float inv = 1.f/(mag + 1e-8f);
    nx *= inv; ny *= inv; nz *= inv;

    float dc = d[r*IMW+c];
    float dmin = fdec(mm[0]), dmax = fdec(mm[1]);
    if (dc == dmin || dc == dmax){ nx = 0.f; ny = 0.f; nz = 0.f; }

    size_t base = (size_t)b*3*HW + pix;
    normal1[base]        = nx;
    normal1[base +   HW] = ny;
    normal1[base + 2*HW] = nz;
}

// ---- per-pixel ICP residual/Jacobian + 27-way reduction ----
__global__ __launch_bounds__(256) void iter_kernel(const float* __restrict__ depth0,
                                                   const float* __restrict__ depth1,
                                                   const float* __restrict__ normal1,
                                                   const float* __restrict__ Kp,
                                                   const float* __restrict__ stateR,
                                                   const float* __restrict__ statet,
                                                   float* __restrict__ acc){
    int b = blockIdx.y;
    int pix = blockIdx.x*256 + threadIdx.x;
    const float fx = Kp[b*4+0], fy = Kp[b*4+1], cx = Kp[b*4+2], cy = Kp[b*4+3];
    float Rm[9];
    #pragma unroll
    for (int i=0;i<9;i++) Rm[i] = stateR[b*9+i];
    float tv[3];
    #pragma unroll
    for (int i=0;i<3;i++) tv[i] = statet[b*3+i];

    int r = pix / IMW, c = pix % IMW;
    float d0 = depth0[(size_t)b*HW + pix];
    float V0x = ((float)c - cx)/fx*d0;
    float V0y = ((float)r - cy)/fy*d0;
    float V0z = d0;

    float X = Rm[0]*V0x + Rm[1]*V0y + Rm[2]*V0z + tv[0];
    float Y = Rm[3]*V0x + Rm[4]*V0y + Rm[5]*V0z + tv[1];
    float Z = Rm[6]*V0x + Rm[7]*V0y + Rm[8]*V0z + tv[2];
    float uu = X/Z*fx + cx;
    float vv = Y/Z*fy + cy;

    bool inview = (uu > 0.f) && (uu < (float)(IMW-1)) && (vv > 0.f) && (vv < (float)(IMH-1));

    float J0=0.f,J1=0.f,J2=0.f,J3=0.f,J4=0.f,J5=0.f,wres=0.f;
    if (inview){
        float u0f = floorf(uu), v0f = floorf(vv);
        int u0 = (int)u0f, v0 = (int)v0f;
        float wu = uu - u0f, wv = vv - v0f;
        float w00 = (1.f-wu)*(1.f-wv), w10 = wu*(1.f-wv), w01 = (1.f-wu)*wv, w11 = wu*wv;
        int i00 = v0*IMW + u0;

        const float* __restrict__ d1 = depth1 + (size_t)b*HW;
        float d00 = d1[i00], d10 = d1[i00+1], d01 = d1[i00+IMW], d11 = d1[i00+IMW+1];
        float pxa = ((float)u0     - cx)/fx, pxb = ((float)(u0+1) - cx)/fx;
        float pya = ((float)v0     - cy)/fy, pyb = ((float)(v0+1) - cy)/fy;
        float rVx = w00*(pxa*d00) + w10*(pxb*d10) + w01*(pxa*d01) + w11*(pxb*d11);
        float rVy = w00*(pya*d00) + w10*(pya*d10) + w01*(pyb*d01) + w11*(pyb*d11);
        float rVz = w00*d00 + w10*d10 + w01*d01 + w11*d11;

        const float* __restrict__ n1x = normal1 + (size_t)b*3*HW;
        const float* __restrict__ n1y = n1x + HW;
        const float* __restrict__ n1z = n1x + 2*HW;
        float n0x = w00*n1x[i00] + w10*n1x[i00+1] + w01*n1x[i00+IMW] + w11*n1x[i00+IMW+1];
        float n0y = w00*n1y[i00] + w10*n1y[i00+1] + w01*n1y[i00+IMW] + w11*n1y[i00+IMW+1];
        float n0z = w00*n1z[i00] + w10*n1z[i00+1] + w01*n1z[i00+IMW] + w11*n1z[i00+IMW+1];

        float dfx = X - rVx, dfy = Y - rVy, dfz = Z - rVz;
        float dnorm = sqrtf(dfx*dfx + dfy*dfy + dfz*dfz + 1e-16f);
        if (dnorm <= 0.1f){
            float res = n0x*dfx + n0y*dfy + n0z*dfz;
            // NtC = n^T R
            float N0 = n0x*Rm[0] + n0y*Rm[3] + n0z*Rm[6];
            float N1 = n0x*Rm[1] + n0y*Rm[4] + n0z*Rm[7];
            float N2 = n0x*Rm[2] + n0y*Rm[5] + n0z*Rm[8];
            // cross(NtC, P0)
            float c0 = N1*V0z - N2*V0y;
            float c1 = N2*V0x - N0*V0z;
            float c2 = N0*V0y - N1*V0x;
            float ndot = fabsf(N2);
            float dsh = d0 - 0.4f;
            float sigz = 0.0012f + 0.0019f*dsh*dsh;
            float sigma = ndot*sigz + 0.001f;
            float invs = 1.f/(sigma + 1e-8f);
            wres = res*invs;
            // J = -[cross, -NtC]/sigma'  => [-cross/s, +NtC/s]
            J0 = -c0*invs; J1 = -c1*invs; J2 = -c2*invs;
            J3 =  N0*invs; J4 =  N1*invs; J5 =  N2*invs;
        }
    }

    float Jv[6] = {J0,J1,J2,J3,J4,J5};
    float vals[27];
    int idx = 0;
    #pragma unroll
    for (int k=0;k<6;k++)
        #pragma unroll
        for (int l=k;l<6;l++) vals[idx++] = Jv[k]*Jv[l];
    #pragma unroll
    for (int k=0;k<6;k++) vals[idx++] = Jv[k]*wres;

    #pragma unroll
    for (int i=0;i<27;i++){
        float v = vals[i];
        #pragma unroll
        for (int off=32; off; off >>= 1) v += __shfl_down(v, off);
        vals[i] = v;
    }

    __shared__ float sacc[4][27];
    int wave = threadIdx.x >> 6, lane = threadIdx.x & 63;
    if (lane == 0){
        #pragma unroll
        for (int i=0;i<27;i++) sacc[wave][i] = vals[i];
    }
    __syncthreads();
    if (threadIdx.x < 27){
        float s = sacc[0][threadIdx.x] + sacc[1][threadIdx.x]
                + sacc[2][threadIdx.x] + sacc[3][threadIdx.x];
        atomicAdd(&acc[b*27 + threadIdx.x], s);
    }
}

// ---- per-batch 6x6 solve + twist update ----
__global__ void solve_kernel(float* __restrict__ acc,
                             float* __restrict__ stateR, float* __restrict__ statet,
                             float* __restrict__ outR, float* __restrict__ outt){
    int b = threadIdx.x;
    if (b >= NB) return;

    float a27[27];
    for (int i=0;i<27;i++) a27[i] = acc[b*27+i];
    // zero for next iteration
    for (int i=0;i<27;i++) acc[b*27+i] = 0.f;

    double A[6][6], rhs[6];
    int idx = 0;
    for (int k=0;k<6;k++)
        for (int l=k;l<6;l++){ A[k][l] = a27[idx]; A[l][k] = a27[idx]; idx++; }
    for (int k=0;k<6;k++) rhs[k] = a27[21+k];

    double tr = 0.0;
    for (int k=0;k<6;k++) tr += A[k][k];
    double lm = tr*1e-6;
    for (int k=0;k<6;k++) A[k][k] += lm;

    // Gauss-Jordan with partial pivoting: M = [A | rhs]
    double M[6][7];
    for (int i=0;i<6;i++){ for (int j=0;j<6;j++) M[i][j]=A[i][j]; M[i][6]=rhs[i]; }
    for (int col=0; col<6; col++){
        int piv = col; double best = fabs(M[col][col]);
        for (int r2=col+1; r2<6; r2++){
            double v = fabs(M[r2][col]);
            if (v > best){ best = v; piv = r2; }
        }
        if (piv != col)
            for (int j=0;j<7;j++){ double tmp = M[col][j]; M[col][j] = M[piv][j]; M[piv][j] = tmp; }
        double p = M[col][col];
        for (int j=col;j<7;j++) M[col][j] /= p;
        for (int r2=0;r2<6;r2++){
            if (r2 == col) continue;
            double f = M[r2][col];
            for (int j=col;j<7;j++) M[r2][j] -= f*M[col][j];
        }
    }
    double xi[6];
    for (int k=0;k<6;k++) xi[k] = M[k][6];

    // dR = twist2mat(-xi[:3])
    double w0 = -xi[0], w1 = -xi[1], w2 = -xi[2];
    double th = sqrt(w0*w0 + w1*w1 + w2*w2 + 1e-24);
    double kx = w0/th, ky = w1/th, kz = w2/th;
    double s = sin(th), cm1 = 1.0 - cos(th);
    double Kv[3][3] = {{0,-kz,ky},{kz,0,-kx},{-ky,kx,0}};
    double K2[3][3];
    for (int i=0;i<3;i++)
        for (int j=0;j<3;j++){
            double acc2 = 0.0;
            for (int k=0;k<3;k++) acc2 += Kv[i][k]*Kv[k][j];
            K2[i][j] = acc2;
        }
    double dR[3][3];
    for (int i=0;i<3;i++)
        for (int j=0;j<3;j++)
            dR[i][j] = (i==j ? 1.0 : 0.0) + s*Kv[i][j] + cm1*K2[i][j];
    double dt[3];
    for (int i=0;i<3;i++)
        dt[i] = -(dR[i][0]*xi[3] + dR[i][1]*xi[4] + dR[i][2]*xi[5]);

    // R_new = R_old @ dR; t_new = R_old @ dt + t_old
    double Ro[3][3];
    for (int i=0;i<3;i++) for (int j=0;j<3;j++) Ro[i][j] = (double)stateR[b*9 + i*3 + j];
    double to[3];
    for (int i=0;i<3;i++) to[i] = (double)statet[b*3+i];

    double Rn[3][3], tn[3];
    for (int i=0;i<3;i++)
        for (int j=0;j<3;j++){
            double acc2 = 0.0;
            for (int k=0;k<3;k++) acc2 += Ro[i][k]*dR[k][j];
            Rn[i][j] = acc2;
        }
    for (int i=0;i<3;i++)
        tn[i] = Ro[i][0]*dt[0] + Ro[i][1]*dt[1] + Ro[i][2]*dt[2] + to[i];

    for (int i=0;i<3;i++)
        for (int j=0;j<3;j++){
            float v = (float)Rn[i][j];
            stateR[b*9 + i*3 + j] = v;
            outR[b*9 + i*3 + j] = v;
        }
    for (int i=0;i<3;i++){
        float v = (float)tn[i];
        statet[b*3+i] = v;
        outt[b*3+i] = v;
    }
}

extern "C" void kernel_launch(void* const* d_in, const int* in_sizes, int n_in,
                              void* d_out, int out_size, void* d_ws, size_t ws_size,
                              hipStream_t stream){
    const float* depth0 = (const float*)d_in[0];
    const float* depth1 = (const float*)d_in[1];
    const float* Kp     = (const float*)d_in[2];
    const float* Rin    = (const float*)d_in[3];
    const float* tin    = (const float*)d_in[4];

    float* out     = (float*)d_out;
    float* outR    = out;
    float* outt    = out + NB*9;
    float* weights = out + NB*12;

    float* normal1 = (float*)d_ws;                        // 3*NB*HW floats (~59 MB)
    float* stateR  = normal1 + (size_t)3*NB*HW;           // NB*9
    float* statet  = stateR + NB*9;                       // NB*3
    unsigned* mm   = (unsigned*)(statet + NB*3);          // 2
    float* acc     = (float*)(mm + 2);                    // NB*27

    fill_weights<<<dim3(NB*HW/4/256), 256, 0, stream>>>(weights);
    init_kernel<<<1, 256, 0, stream>>>(Rin, tin, stateR, statet, mm, acc);
    minmax_kernel<<<dim3(1200), 256, 0, stream>>>(depth1, mm);
    normal_kernel<<<dim3(HW/256, NB), 256, 0, stream>>>(depth1, Kp, mm, normal1);
    for (int it = 0; it < 3; it++){
        iter_kernel<<<dim3(HW/256, NB), 256, 0, stream>>>(depth0, depth1, normal1, Kp, stateR, statet, acc);
        solve_kernel<<<1, 64, 0, stream>>>(acc, stateR, statet, outR, outt);
    }
}

// Round 2
// 397.607 us; speedup vs baseline: 1.9541x; 1.9541x over previous
//
#include <hip/hip_runtime.h>

#define IMH 480
#define IMW 640
#define HW (IMH*IMW)
#define NB 16

// iter_kernel: pixels-per-thread and blocks-per-batch (75*256*16 == HW exactly)
#define PPT 16
#define BPB 75

// ---- order-preserving float<->uint encoding (for atomic min/max) ----
__device__ inline unsigned fenc(float x){
    unsigned u = __float_as_uint(x);
    return (u & 0x80000000u) ? ~u : (u | 0x80000000u);
}
__device__ inline float fdec(unsigned e){
    unsigned u = (e & 0x80000000u) ? (e & 0x7FFFFFFFu) : ~e;
    return __uint_as_float(u);
}

// ---- weights = 1.0 ----
__global__ __launch_bounds__(256) void fill_weights(float* __restrict__ w){
    int i = blockIdx.x*256 + threadIdx.x;
    if (i < NB*HW/4) ((float4*)w)[i] = make_float4(1.f,1.f,1.f,1.f);
}

// ---- init: copy R,t to state, zero accumulators, init min/max ----
__global__ void init_kernel(const float* __restrict__ Rin, const float* __restrict__ tin,
                            float* __restrict__ stateR, float* __restrict__ statet,
                            unsigned* __restrict__ mm, float* __restrict__ acc){
    int i = threadIdx.x;
    if (i < NB*9) stateR[i] = Rin[i];
    if (i < NB*3) statet[i] = tin[i];
    if (i == 0){ mm[0] = 0xFFFFFFFFu; mm[1] = 0u; }
    for (int k = i; k < NB*27; k += 256) acc[k] = 0.f;
}

// ---- global min/max of depth1 ----
__global__ __launch_bounds__(256) void minmax_kernel(const float* __restrict__ d, unsigned* __restrict__ mm){
    unsigned lmin = 0xFFFFFFFFu, lmax = 0u;
    const int total = NB*HW;
    for (int i = blockIdx.x*256 + threadIdx.x; i < total; i += gridDim.x*256){
        unsigned e = fenc(d[i]);
        lmin = min(lmin, e); lmax = max(lmax, e);
    }
    #pragma unroll
    for (int off = 32; off; off >>= 1){
        lmin = min(lmin, (unsigned)__shfl_down((int)lmin, off));
        lmax = max(lmax, (unsigned)__shfl_down((int)lmax, off));
    }
    if ((threadIdx.x & 63) == 0){ atomicMin(&mm[0], lmin); atomicMax(&mm[1], lmax); }
}

// ---- normal1: sobel over vertex1 (recomputed from depth1), cross, normalize, mask ----
__global__ __launch_bounds__(256) void normal_kernel(const float* __restrict__ depth1,
                                                     const float* __restrict__ Kp,
                                                     const unsigned* __restrict__ mm,
                                                     float* __restrict__ normal1){
    int b = blockIdx.y;
    int pix = blockIdx.x*256 + threadIdx.x;
    int r = pix / IMW, c = pix % IMW;
    const float fx = Kp[b*4+0], fy = Kp[b*4+1], cx = Kp[b*4+2], cy = Kp[b*4+3];
    const float* __restrict__ d = depth1 + (size_t)b*HW;
    int rm = max(r-1,0), rp = min(r+1,IMH-1), cm = max(c-1,0), cp = min(c+1,IMW-1);

    auto vert = [&](int rr, int cc, float v[3]){
        float dd = d[rr*IMW+cc];
        v[0] = ((float)cc - cx)/fx*dd;
        v[1] = ((float)rr - cy)/fy*dd;
        v[2] = dd;
    };
    float va[3],vb[3],vc2[3],vd[3],ve[3],vf[3],vg[3],vh[3];
    vert(rm,cm,va); vert(rm,c,vb);  vert(rm,cp,vc2);
    vert(r ,cm,vd);                 vert(r ,cp,ve);
    vert(rp,cm,vf); vert(rp,c,vg);  vert(rp,cp,vh);

    float dx[3], dy[3];
    #pragma unroll
    for (int k=0;k<3;k++){
        dx[k] = (vc2[k]-va[k]) + 2.f*(ve[k]-vd[k]) + (vh[k]-vf[k]);
        dy[k] = (vf[k]-va[k]) + 2.f*(vg[k]-vb[k]) + (vh[k]-vc2[k]);
    }
    float nx = dx[1]*dy[2] - dx[2]*dy[1];
    float ny = dx[2]*dy[0] - dx[0]*dy[2];
    float nz = dx[0]*dy[1] - dx[1]*dy[0];
    float mag = sqrtf(nx*nx + ny*ny + nz*nz + 1e-16f);
    float inv = 1.f/(mag + 1e-8f);
    nx *= inv; ny *= inv; nz *= inv;

    float dc = d[r*IMW+c];
    float dmin = fdec(mm[0]), dmax = fdec(mm[1]);
    if (dc == dmin || dc == dmax){ nx = 0.f; ny = 0.f; nz = 0.f; }

    size_t base = (size_t)b*3*HW + pix;
    normal1[base]        = nx;
    normal1[base +   HW] = ny;
    normal1[base + 2*HW] = nz;
}

// ---- per-pixel ICP residual/Jacobian; 27 sums accumulated in registers over PPT pixels ----
__global__ __launch_bounds__(256) void iter_kernel(const float* __restrict__ depth0,
                                                   const float* __restrict__ depth1,
                                                   const float* __restrict__ normal1,
                                                   const float* __restrict__ Kp,
                                                   const float* __restrict__ stateR,
                                                   const float* __restrict__ statet,
                                                   float* __restrict__ acc){
    const int b = blockIdx.y;
    const float fx = Kp[b*4+0], fy = Kp[b*4+1], cx = Kp[b*4+2], cy = Kp[b*4+3];
    float Rm[9];
    #pragma unroll
    for (int i=0;i<9;i++) Rm[i] = stateR[b*9+i];
    float tv[3];
    #pragma unroll
    for (int i=0;i<3;i++) tv[i] = statet[b*3+i];

    const float* __restrict__ d0p = depth0 + (size_t)b*HW;
    const float* __restrict__ d1  = depth1 + (size_t)b*HW;
    const float* __restrict__ n1x = normal1 + (size_t)b*3*HW;
    const float* __restrict__ n1y = n1x + HW;
    const float* __restrict__ n1z = n1x + 2*HW;

    float accv[27];
    #pragma unroll
    for (int i=0;i<27;i++) accv[i] = 0.f;

    const int tid = blockIdx.x*256 + threadIdx.x;
    const int stride = BPB*256;

    #pragma unroll 1
    for (int pp = 0; pp < PPT; pp++){
        int pix = tid + pp*stride;
        int r = pix / IMW, c = pix % IMW;
        float d0 = d0p[pix];
        float V0x = ((float)c - cx)/fx*d0;
        float V0y = ((float)r - cy)/fy*d0;
        float V0z = d0;

        float X = Rm[0]*V0x + Rm[1]*V0y + Rm[2]*V0z + tv[0];
        float Y = Rm[3]*V0x + Rm[4]*V0y + Rm[5]*V0z + tv[1];
        float Z = Rm[6]*V0x + Rm[7]*V0y + Rm[8]*V0z + tv[2];
        float uu = X/Z*fx + cx;
        float vv = Y/Z*fy + cy;

        bool inview = (uu > 0.f) && (uu < (float)(IMW-1)) && (vv > 0.f) && (vv < (float)(IMH-1));

        float J0=0.f,J1=0.f,J2=0.f,J3=0.f,J4=0.f,J5=0.f,wres=0.f;
        if (inview){
            float u0f = floorf(uu), v0f = floorf(vv);
            int u0 = (int)u0f, v0 = (int)v0f;
            float wu = uu - u0f, wv = vv - v0f;
            float w00 = (1.f-wu)*(1.f-wv), w10 = wu*(1.f-wv), w01 = (1.f-wu)*wv, w11 = wu*wv;
            int i00 = v0*IMW + u0;

            float d00 = d1[i00], d10 = d1[i00+1], d01 = d1[i00+IMW], d11 = d1[i00+IMW+1];
            float pxa = ((float)u0     - cx)/fx, pxb = ((float)(u0+1) - cx)/fx;
            float pya = ((float)v0     - cy)/fy, pyb = ((float)(v0+1) - cy)/fy;
            float rVx = w00*(pxa*d00) + w10*(pxb*d10) + w01*(pxa*d01) + w11*(pxb*d11);
            float rVy = w00*(pya*d00) + w10*(pya*d10) + w01*(pyb*d01) + w11*(pyb*d11);
            float rVz = w00*d00 + w10*d10 + w01*d01 + w11*d11;

            float n0x = w00*n1x[i00] + w10*n1x[i00+1] + w01*n1x[i00+IMW] + w11*n1x[i00+IMW+1];
            float n0y = w00*n1y[i00] + w10*n1y[i00+1] + w01*n1y[i00+IMW] + w11*n1y[i00+IMW+1];
            float n0z = w00*n1z[i00] + w10*n1z[i00+1] + w01*n1z[i00+IMW] + w11*n1z[i00+IMW+1];

            float dfx = X - rVx, dfy = Y - rVy, dfz = Z - rVz;
            float dnorm = sqrtf(dfx*dfx + dfy*dfy + dfz*dfz + 1e-16f);
            if (dnorm <= 0.1f){
                float res = n0x*dfx + n0y*dfy + n0z*dfz;
                // NtC = n^T R
                float N0 = n0x*Rm[0] + n0y*Rm[3] + n0z*Rm[6];
                float N1 = n0x*Rm[1] + n0y*Rm[4] + n0z*Rm[7];
                float N2 = n0x*Rm[2] + n0y*Rm[5] + n0z*Rm[8];
                // cross(NtC, P0)
                float c0 = N1*V0z - N2*V0y;
                float c1 = N2*V0x - N0*V0z;
                float c2 = N0*V0y - N1*V0x;
                float ndot = fabsf(N2);
                float dsh = d0 - 0.4f;
                float sigz = 0.0012f + 0.0019f*dsh*dsh;
                float sigma = ndot*sigz + 0.001f;
                float invs = 1.f/(sigma + 1e-8f);
                wres = res*invs;
                J0 = -c0*invs; J1 = -c1*invs; J2 = -c2*invs;
                J3 =  N0*invs; J4 =  N1*invs; J5 =  N2*invs;
            }
        }

        float Jv[6] = {J0,J1,J2,J3,J4,J5};
        int idx = 0;
        #pragma unroll
        for (int k=0;k<6;k++)
            #pragma unroll
            for (int l=k;l<6;l++){ accv[idx] += Jv[k]*Jv[l]; idx++; }
        #pragma unroll
        for (int k=0;k<6;k++){ accv[idx] += Jv[k]*wres; idx++; }
    }

    // one wave-level reduction per thread (amortized over PPT pixels)
    #pragma unroll
    for (int i=0;i<27;i++){
        float v = accv[i];
        #pragma unroll
        for (int off=32; off; off >>= 1) v += __shfl_down(v, off);
        accv[i] = v;
    }

    __shared__ float sacc[4][27];
    int wave = threadIdx.x >> 6, lane = threadIdx.x & 63;
    if (lane == 0){
        #pragma unroll
        for (int i=0;i<27;i++) sacc[wave][i] = accv[i];
    }
    __syncthreads();
    if (threadIdx.x < 27){
        float s = sacc[0][threadIdx.x] + sacc[1][threadIdx.x]
                + sacc[2][threadIdx.x] + sacc[3][threadIdx.x];
        atomicAdd(&acc[b*27 + threadIdx.x], s);
    }
}

// ---- per-batch 6x6 solve + twist update ----
__global__ void solve_kernel(float* __restrict__ acc,
                             float* __restrict__ stateR, float* __restrict__ statet,
                             float* __restrict__ outR, float* __restrict__ outt){
    int b = threadIdx.x;
    if (b >= NB) return;

    float a27[27];
    for (int i=0;i<27;i++) a27[i] = acc[b*27+i];
    // zero for next iteration
    for (int i=0;i<27;i++) acc[b*27+i] = 0.f;

    double A[6][6], rhs[6];
    int idx = 0;
    for (int k=0;k<6;k++)
        for (int l=k;l<6;l++){ A[k][l] = a27[idx]; A[l][k] = a27[idx]; idx++; }
    for (int k=0;k<6;k++) rhs[k] = a27[21+k];

    double tr = 0.0;
    for (int k=0;k<6;k++) tr += A[k][k];
    double lm = tr*1e-6;
    for (int k=0;k<6;k++) A[k][k] += lm;

    // Gauss-Jordan with partial pivoting: M = [A | rhs]
    double M[6][7];
    for (int i=0;i<6;i++){ for (int j=0;j<6;j++) M[i][j]=A[i][j]; M[i][6]=rhs[i]; }
    for (int col=0; col<6; col++){
        int piv = col; double best = fabs(M[col][col]);
        for (int r2=col+1; r2<6; r2++){
            double v = fabs(M[r2][col]);
            if (v > best){ best = v; piv = r2; }
        }
        if (piv != col)
            for (int j=0;j<7;j++){ double tmp = M[col][j]; M[col][j] = M[piv][j]; M[piv][j] = tmp; }
        double p = M[col][col];
        for (int j=col;j<7;j++) M[col][j] /= p;
        for (int r2=0;r2<6;r2++){
            if (r2 == col) continue;
            double f = M[r2][col];
            for (int j=col;j<7;j++) M[r2][j] -= f*M[col][j];
        }
    }
    double xi[6];
    for (int k=0;k<6;k++) xi[k] = M[k][6];

    // dR = twist2mat(-xi[:3])
    double w0 = -xi[0], w1 = -xi[1], w2 = -xi[2];
    double th = sqrt(w0*w0 + w1*w1 + w2*w2 + 1e-24);
    double kx = w0/th, ky = w1/th, kz = w2/th;
    double s = sin(th), cm1 = 1.0 - cos(th);
    double Kv[3][3] = {{0,-kz,ky},{kz,0,-kx},{-ky,kx,0}};
    double K2[3][3];
    for (int i=0;i<3;i++)
        for (int j=0;j<3;j++){
            double acc2 = 0.0;
            for (int k=0;k<3;k++) acc2 += Kv[i][k]*Kv[k][j];
            K2[i][j] = acc2;
        }
    double dR[3][3];
    for (int i=0;i<3;i++)
        for (int j=0;j<3;j++)
            dR[i][j] = (i==j ? 1.0 : 0.0) + s*Kv[i][j] + cm1*K2[i][j];
    double dt[3];
    for (int i=0;i<3;i++)
        dt[i] = -(dR[i][0]*xi[3] + dR[i][1]*xi[4] + dR[i][2]*xi[5]);

    // R_new = R_old @ dR; t_new = R_old @ dt + t_old
    double Ro[3][3];
    for (int i=0;i<3;i++) for (int j=0;j<3;j++) Ro[i][j] = (double)stateR[b*9 + i*3 + j];
    double to[3];
    for (int i=0;i<3;i++) to[i] = (double)statet[b*3+i];

    double Rn[3][3], tn[3];
    for (int i=0;i<3;i++)
        for (int j=0;j<3;j++){
            double acc2 = 0.0;
            for (int k=0;k<3;k++) acc2 += Ro[i][k]*dR[k][j];
            Rn[i][j] = acc2;
        }
    for (int i=0;i<3;i++)
        tn[i] = Ro[i][0]*dt[0] + Ro[i][1]*dt[1] + Ro[i][2]*dt[2] + to[i];

    for (int i=0;i<3;i++)
        for (int j=0;j<3;j++){
            float v = (float)Rn[i][j];
            stateR[b*9 + i*3 + j] = v;
            outR[b*9 + i*3 + j] = v;
        }
    for (int i=0;i<3;i++){
        float v = (float)tn[i];
        statet[b*3+i] = v;
        outt[b*3+i] = v;
    }
}

extern "C" void kernel_launch(void* const* d_in, const int* in_sizes, int n_in,
                              void* d_out, int out_size, void* d_ws, size_t ws_size,
                              hipStream_t stream){
    const float* depth0 = (const float*)d_in[0];
    const float* depth1 = (const float*)d_in[1];
    const float* Kp     = (const float*)d_in[2];
    const float* Rin    = (const float*)d_in[3];
    const float* tin    = (const float*)d_in[4];

    float* out     = (float*)d_out;
    float* outR    = out;
    float* outt    = out + NB*9;
    float* weights = out + NB*12;

    float* normal1 = (float*)d_ws;                        // 3*NB*HW floats (~59 MB)
    float* stateR  = normal1 + (size_t)3*NB*HW;           // NB*9
    float* statet  = stateR + NB*9;                       // NB*3
    unsigned* mm   = (unsigned*)(statet + NB*3);          // 2
    float* acc     = (float*)(mm + 2);                    // NB*27

    fill_weights<<<dim3(NB*HW/4/256), 256, 0, stream>>>(weights);
    init_kernel<<<1, 256, 0, stream>>>(Rin, tin, stateR, statet, mm, acc);
    minmax_kernel<<<dim3(1200), 256, 0, stream>>>(depth1, mm);
    normal_kernel<<<dim3(HW/256, NB), 256, 0, stream>>>(depth1, Kp, mm, normal1);
    for (int it = 0; it < 3; it++){
        iter_kernel<<<dim3(BPB, NB), 256, 0, stream>>>(depth0, depth1, normal1, Kp, stateR, statet, acc);
        solve_kernel<<<1, 64, 0, stream>>>(acc, stateR, statet, outR, outt);
    }
}

// Round 3
// 294.312 us; speedup vs baseline: 2.6400x; 1.3510x over previous
//
#include <hip/hip_runtime.h>

#define IMH 480
#define IMW 640
#define HW (IMH*IMW)
#define NB 16

// iter_kernel: pixels-per-thread and blocks-per-batch (75*256*16 == HW exactly)
#define PPT 16
#define BPB 75

// ---- order-preserving float<->uint encoding (for atomic min/max) ----
__device__ inline unsigned fenc(float x){
    unsigned u = __float_as_uint(x);
    return (u & 0x80000000u) ? ~u : (u | 0x80000000u);
}
__device__ inline float fdec(unsigned e){
    unsigned u = (e & 0x80000000u) ? (e & 0x7FFFFFFFu) : ~e;
    return __uint_as_float(u);
}

// ---- weights = 1.0 ----
__global__ __launch_bounds__(256) void fill_weights(float* __restrict__ w){
    int i = blockIdx.x*256 + threadIdx.x;
    if (i < NB*HW/4) ((float4*)w)[i] = make_float4(1.f,1.f,1.f,1.f);
}

// ---- init: copy R,t to state, zero accumulators, init min/max ----
__global__ void init_kernel(const float* __restrict__ Rin, const float* __restrict__ tin,
                            float* __restrict__ stateR, float* __restrict__ statet,
                            unsigned* __restrict__ mm, float* __restrict__ acc){
    int i = threadIdx.x;
    if (i < NB*9) stateR[i] = Rin[i];
    if (i < NB*3) statet[i] = tin[i];
    if (i == 0){ mm[0] = 0xFFFFFFFFu; mm[1] = 0u; }
    for (int k = i; k < NB*27; k += 256) acc[k] = 0.f;
}

// ---- global min/max of depth1: float4 loads, block-level combine, 1 atomic/block ----
__global__ __launch_bounds__(256) void minmax_kernel(const float4* __restrict__ d, unsigned* __restrict__ mm){
    unsigned lmin = 0xFFFFFFFFu, lmax = 0u;
    const int total4 = NB*HW/4;
    for (int i = blockIdx.x*256 + threadIdx.x; i < total4; i += gridDim.x*256){
        float4 v = d[i];
        unsigned e0 = fenc(v.x), e1 = fenc(v.y), e2 = fenc(v.z), e3 = fenc(v.w);
        lmin = min(lmin, min(min(e0,e1), min(e2,e3)));
        lmax = max(lmax, max(max(e0,e1), max(e2,e3)));
    }
    #pragma unroll
    for (int off = 32; off; off >>= 1){
        lmin = min(lmin, (unsigned)__shfl_down((int)lmin, off));
        lmax = max(lmax, (unsigned)__shfl_down((int)lmax, off));
    }
    __shared__ unsigned smin[4], smax[4];
    int wave = threadIdx.x >> 6, lane = threadIdx.x & 63;
    if (lane == 0){ smin[wave] = lmin; smax[wave] = lmax; }
    __syncthreads();
    if (threadIdx.x == 0){
        unsigned bmin = min(min(smin[0],smin[1]), min(smin[2],smin[3]));
        unsigned bmax = max(max(smax[0],smax[1]), max(smax[2],smax[3]));
        atomicMin(&mm[0], bmin);
        atomicMax(&mm[1], bmax);
    }
}

// ---- normal1: sobel over vertex1 (recomputed from depth1), cross, normalize, mask ----
__global__ __launch_bounds__(256) void normal_kernel(const float* __restrict__ depth1,
                                                     const float* __restrict__ Kp,
                                                     const unsigned* __restrict__ mm,
                                                     float* __restrict__ normal1){
    int b = blockIdx.y;
    int pix = blockIdx.x*256 + threadIdx.x;
    int r = pix / IMW, c = pix % IMW;
    const float fx = Kp[b*4+0], fy = Kp[b*4+1], cx = Kp[b*4+2], cy = Kp[b*4+3];
    const float* __restrict__ d = depth1 + (size_t)b*HW;
    int rm = max(r-1,0), rp = min(r+1,IMH-1), cm = max(c-1,0), cp = min(c+1,IMW-1);

    auto vert = [&](int rr, int cc, float v[3]){
        float dd = d[rr*IMW+cc];
        v[0] = ((float)cc - cx)/fx*dd;
        v[1] = ((float)rr - cy)/fy*dd;
        v[2] = dd;
    };
    float va[3],vb[3],vc2[3],vd[3],ve[3],vf[3],vg[3],vh[3];
    vert(rm,cm,va); vert(rm,c,vb);  vert(rm,cp,vc2);
    vert(r ,cm,vd);                 vert(r ,cp,ve);
    vert(rp,cm,vf); vert(rp,c,vg);  vert(rp,cp,vh);

    float dx[3], dy[3];
    #pragma unroll
    for (int k=0;k<3;k++){
        dx[k] = (vc2[k]-va[k]) + 2.f*(ve[k]-vd[k]) + (vh[k]-vf[k]);
        dy[k] = (vf[k]-va[k]) + 2.f*(vg[k]-vb[k]) + (vh[k]-vc2[k]);
    }
    float nx = dx[1]*dy[2] - dx[2]*dy[1];
    float ny = dx[2]*dy[0] - dx[0]*dy[2];
    float nz = dx[0]*dy[1] - dx[1]*dy[0];
    float mag = sqrtf(nx*nx + ny*ny + nz*nz + 1e-16f);
    float inv = 1.f/(mag + 1e-8f);
    nx *= inv; ny *= inv; nz *= inv;

    float dc = d[r*IMW+c];
    float dmin = fdec(mm[0]), dmax = fdec(mm[1]);
    if (dc == dmin || dc == dmax){ nx = 0.f; ny = 0.f; nz = 0.f; }

    size_t base = (size_t)b*3*HW + pix;
    normal1[base]        = nx;
    normal1[base +   HW] = ny;
    normal1[base + 2*HW] = nz;
}

// ---- per-pixel ICP residual/Jacobian; 27 sums accumulated in registers over PPT pixels ----
__global__ __launch_bounds__(256) void iter_kernel(const float* __restrict__ depth0,
                                                   const float* __restrict__ depth1,
                                                   const float* __restrict__ normal1,
                                                   const float* __restrict__ Kp,
                                                   const float* __restrict__ stateR,
                                                   const float* __restrict__ statet,
                                                   float* __restrict__ acc){
    const int b = blockIdx.y;
    const float fx = Kp[b*4+0], fy = Kp[b*4+1], cx = Kp[b*4+2], cy = Kp[b*4+3];
    float Rm[9];
    #pragma unroll
    for (int i=0;i<9;i++) Rm[i] = stateR[b*9+i];
    float tv[3];
    #pragma unroll
    for (int i=0;i<3;i++) tv[i] = statet[b*3+i];

    const float* __restrict__ d0p = depth0 + (size_t)b*HW;
    const float* __restrict__ d1  = depth1 + (size_t)b*HW;
    const float* __restrict__ n1x = normal1 + (size_t)b*3*HW;
    const float* __restrict__ n1y = n1x + HW;
    const float* __restrict__ n1z = n1x + 2*HW;

    float accv[27];
    #pragma unroll
    for (int i=0;i<27;i++) accv[i] = 0.f;

    const int tid = blockIdx.x*256 + threadIdx.x;
    const int stride = BPB*256;

    #pragma unroll 1
    for (int pp = 0; pp < PPT; pp++){
        int pix = tid + pp*stride;
        int r = pix / IMW, c = pix % IMW;
        float d0 = d0p[pix];
        float V0x = ((float)c - cx)/fx*d0;
        float V0y = ((float)r - cy)/fy*d0;
        float V0z = d0;

        float X = Rm[0]*V0x + Rm[1]*V0y + Rm[2]*V0z + tv[0];
        float Y = Rm[3]*V0x + Rm[4]*V0y + Rm[5]*V0z + tv[1];
        float Z = Rm[6]*V0x + Rm[7]*V0y + Rm[8]*V0z + tv[2];
        float uu = X/Z*fx + cx;
        float vv = Y/Z*fy + cy;

        bool inview = (uu > 0.f) && (uu < (float)(IMW-1)) && (vv > 0.f) && (vv < (float)(IMH-1));

        float J0=0.f,J1=0.f,J2=0.f,J3=0.f,J4=0.f,J5=0.f,wres=0.f;
        if (inview){
            float u0f = floorf(uu), v0f = floorf(vv);
            int u0 = (int)u0f, v0 = (int)v0f;
            float wu = uu - u0f, wv = vv - v0f;
            float w00 = (1.f-wu)*(1.f-wv), w10 = wu*(1.f-wv), w01 = (1.f-wu)*wv, w11 = wu*wv;
            int i00 = v0*IMW + u0;

            float d00 = d1[i00], d10 = d1[i00+1], d01 = d1[i00+IMW], d11 = d1[i00+IMW+1];
            float pxa = ((float)u0     - cx)/fx, pxb = ((float)(u0+1) - cx)/fx;
            float pya = ((float)v0     - cy)/fy, pyb = ((float)(v0+1) - cy)/fy;
            float rVx = w00*(pxa*d00) + w10*(pxb*d10) + w01*(pxa*d01) + w11*(pxb*d11);
            float rVy = w00*(pya*d00) + w10*(pya*d10) + w01*(pyb*d01) + w11*(pyb*d11);
            float rVz = w00*d00 + w10*d10 + w01*d01 + w11*d11;

            float n0x = w00*n1x[i00] + w10*n1x[i00+1] + w01*n1x[i00+IMW] + w11*n1x[i00+IMW+1];
            float n0y = w00*n1y[i00] + w10*n1y[i00+1] + w01*n1y[i00+IMW] + w11*n1y[i00+IMW+1];
            float n0z = w00*n1z[i00] + w10*n1z[i00+1] + w01*n1z[i00+IMW] + w11*n1z[i00+IMW+1];

            float dfx = X - rVx, dfy = Y - rVy, dfz = Z - rVz;
            float dnorm = sqrtf(dfx*dfx + dfy*dfy + dfz*dfz + 1e-16f);
            if (dnorm <= 0.1f){
                float res = n0x*dfx + n0y*dfy + n0z*dfz;
                // NtC = n^T R
                float N0 = n0x*Rm[0] + n0y*Rm[3] + n0z*Rm[6];
                float N1 = n0x*Rm[1] + n0y*Rm[4] + n0z*Rm[7];
                float N2 = n0x*Rm[2] + n0y*Rm[5] + n0z*Rm[8];
                // cross(NtC, P0)
                float c0 = N1*V0z - N2*V0y;
                float c1 = N2*V0x - N0*V0z;
                float c2 = N0*V0y - N1*V0x;
                float ndot = fabsf(N2);
                float dsh = d0 - 0.4f;
                float sigz = 0.0012f + 0.0019f*dsh*dsh;
                float sigma = ndot*sigz + 0.001f;
                float invs = 1.f/(sigma + 1e-8f);
                wres = res*invs;
                J0 = -c0*invs; J1 = -c1*invs; J2 = -c2*invs;
                J3 =  N0*invs; J4 =  N1*invs; J5 =  N2*invs;
            }
        }

        float Jv[6] = {J0,J1,J2,J3,J4,J5};
        int idx = 0;
        #pragma unroll
        for (int k=0;k<6;k++)
            #pragma unroll
            for (int l=k;l<6;l++){ accv[idx] += Jv[k]*Jv[l]; idx++; }
        #pragma unroll
        for (int k=0;k<6;k++){ accv[idx] += Jv[k]*wres; idx++; }
    }

    // one wave-level reduction per thread (amortized over PPT pixels)
    #pragma unroll
    for (int i=0;i<27;i++){
        float v = accv[i];
        #pragma unroll
        for (int off=32; off; off >>= 1) v += __shfl_down(v, off);
        accv[i] = v;
    }

    __shared__ float sacc[4][27];
    int wave = threadIdx.x >> 6, lane = threadIdx.x & 63;
    if (lane == 0){
        #pragma unroll
        for (int i=0;i<27;i++) sacc[wave][i] = accv[i];
    }
    __syncthreads();
    if (threadIdx.x < 27){
        float s = sacc[0][threadIdx.x] + sacc[1][threadIdx.x]
                + sacc[2][threadIdx.x] + sacc[3][threadIdx.x];
        atomicAdd(&acc[b*27 + threadIdx.x], s);
    }
}

// ---- per-batch 6x6 solve + twist update ----
__global__ void solve_kernel(float* __restrict__ acc,
                             float* __restrict__ stateR, float* __restrict__ statet,
                             float* __restrict__ outR, float* __restrict__ outt){
    int b = threadIdx.x;
    if (b >= NB) return;

    float a27[27];
    for (int i=0;i<27;i++) a27[i] = acc[b*27+i];
    // zero for next iteration
    for (int i=0;i<27;i++) acc[b*27+i] = 0.f;

    double A[6][6], rhs[6];
    int idx = 0;
    for (int k=0;k<6;k++)
        for (int l=k;l<6;l++){ A[k][l] = a27[idx]; A[l][k] = a27[idx]; idx++; }
    for (int k=0;k<6;k++) rhs[k] = a27[21+k];

    double tr = 0.0;
    for (int k=0;k<6;k++) tr += A[k][k];
    double lm = tr*1e-6;
    for (int k=0;k<6;k++) A[k][k] += lm;

    // Gauss-Jordan with partial pivoting: M = [A | rhs]
    double M[6][7];
    for (int i=0;i<6;i++){ for (int j=0;j<6;j++) M[i][j]=A[i][j]; M[i][6]=rhs[i]; }
    for (int col=0; col<6; col++){
        int piv = col; double best = fabs(M[col][col]);
        for (int r2=col+1; r2<6; r2++){
            double v = fabs(M[r2][col]);
            if (v > best){ best = v; piv = r2; }
        }
        if (piv != col)
            for (int j=0;j<7;j++){ double tmp = M[col][j]; M[col][j] = M[piv][j]; M[piv][j] = tmp; }
        double p = M[col][col];
        for (int j=col;j<7;j++) M[col][j] /= p;
        for (int r2=0;r2<6;r2++){
            if (r2 == col) continue;
            double f = M[r2][col];
            for (int j=col;j<7;j++) M[r2][j] -= f*M[col][j];
        }
    }
    double xi[6];
    for (int k=0;k<6;k++) xi[k] = M[k][6];

    // dR = twist2mat(-xi[:3])
    double w0 = -xi[0], w1 = -xi[1], w2 = -xi[2];
    double th = sqrt(w0*w0 + w1*w1 + w2*w2 + 1e-24);
    double kx = w0/th, ky = w1/th, kz = w2/th;
    double s = sin(th), cm1 = 1.0 - cos(th);
    double Kv[3][3] = {{0,-kz,ky},{kz,0,-kx},{-ky,kx,0}};
    double K2[3][3];
    for (int i=0;i<3;i++)
        for (int j=0;j<3;j++){
            double acc2 = 0.0;
            for (int k=0;k<3;k++) acc2 += Kv[i][k]*Kv[k][j];
            K2[i][j] = acc2;
        }
    double dR[3][3];
    for (int i=0;i<3;i++)
        for (int j=0;j<3;j++)
            dR[i][j] = (i==j ? 1.0 : 0.0) + s*Kv[i][j] + cm1*K2[i][j];
    double dt[3];
    for (int i=0;i<3;i++)
        dt[i] = -(dR[i][0]*xi[3] + dR[i][1]*xi[4] + dR[i][2]*xi[5]);

    // R_new = R_old @ dR; t_new = R_old @ dt + t_old
    double Ro[3][3];
    for (int i=0;i<3;i++) for (int j=0;j<3;j++) Ro[i][j] = (double)stateR[b*9 + i*3 + j];
    double to[3];
    for (int i=0;i<3;i++) to[i] = (double)statet[b*3+i];

    double Rn[3][3], tn[3];
    for (int i=0;i<3;i++)
        for (int j=0;j<3;j++){
            double acc2 = 0.0;
            for (int k=0;k<3;k++) acc2 += Ro[i][k]*dR[k][j];
            Rn[i][j] = acc2;
        }
    for (int i=0;i<3;i++)
        tn[i] = Ro[i][0]*dt[0] + Ro[i][1]*dt[1] + Ro[i][2]*dt[2] + to[i];

    for (int i=0;i<3;i++)
        for (int j=0;j<3;j++){
            float v = (float)Rn[i][j];
            stateR[b*9 + i*3 + j] = v;
            outR[b*9 + i*3 + j] = v;
        }
    for (int i=0;i<3;i++){
        float v = (float)tn[i];
        statet[b*3+i] = v;
        outt[b*3+i] = v;
    }
}

extern "C" void kernel_launch(void* const* d_in, const int* in_sizes, int n_in,
                              void* d_out, int out_size, void* d_ws, size_t ws_size,
                              hipStream_t stream){
    const float* depth0 = (const float*)d_in[0];
    const float* depth1 = (const float*)d_in[1];
    const float* Kp     = (const float*)d_in[2];
    const float* Rin    = (const float*)d_in[3];
    const float* tin    = (const float*)d_in[4];

    float* out     = (float*)d_out;
    float* outR    = out;
    float* outt    = out + NB*9;
    float* weights = out + NB*12;

    float* normal1 = (float*)d_ws;                        // 3*NB*HW floats (~59 MB)
    float* stateR  = normal1 + (size_t)3*NB*HW;           // NB*9
    float* statet  = stateR + NB*9;                       // NB*3
    unsigned* mm   = (unsigned*)(statet + NB*3);          // 2
    float* acc     = (float*)(mm + 2);                    // NB*27

    fill_weights<<<dim3(NB*HW/4/256), 256, 0, stream>>>(weights);
    init_kernel<<<1, 256, 0, stream>>>(Rin, tin, stateR, statet, mm, acc);
    minmax_kernel<<<dim3(256), 256, 0, stream>>>((const float4*)depth1, mm);
    normal_kernel<<<dim3(HW/256, NB), 256, 0, stream>>>(depth1, Kp, mm, normal1);
    for (int it = 0; it < 3; it++){
        iter_kernel<<<dim3(BPB, NB), 256, 0, stream>>>(depth0, depth1, normal1, Kp, stateR, statet, acc);
        solve_kernel<<<1, 64, 0, stream>>>(acc, stateR, statet, outR, outt);
    }
}

// Round 4
// 273.440 us; speedup vs baseline: 2.8415x; 1.0763x over previous
//
#include <hip/hip_runtime.h>

#define IMH 480
#define IMW 640
#define HW (IMH*IMW)
#define NB 16

// iter_kernel: pixels-per-thread and blocks-per-batch (100*256*12 == HW exactly)
#define PPT 12
#define BPB 100
#define STRIDE_PX (BPB*256)        // 25600 px
#define STRIDE_ROWS (STRIDE_PX/IMW) // 40 rows exactly

// ---- order-preserving float<->uint encoding (for atomic min/max) ----
__device__ inline unsigned fenc(float x){
    unsigned u = __float_as_uint(x);
    return (u & 0x80000000u) ? ~u : (u | 0x80000000u);
}
__device__ inline float fdec(unsigned e){
    unsigned u = (e & 0x80000000u) ? (e & 0x7FFFFFFFu) : ~e;
    return __uint_as_float(u);
}

// ---- init: copy R,t to state, zero accumulators, init min/max ----
__global__ void init_kernel(const float* __restrict__ Rin, const float* __restrict__ tin,
                            float* __restrict__ stateR, float* __restrict__ statet,
                            unsigned* __restrict__ mm, float* __restrict__ acc){
    int i = threadIdx.x;
    if (i < NB*9) stateR[i] = Rin[i];
    if (i < NB*3) statet[i] = tin[i];
    if (i == 0){ mm[0] = 0xFFFFFFFFu; mm[1] = 0u; }
    for (int k = i; k < NB*27; k += 256) acc[k] = 0.f;
}

// ---- global min/max of depth1: float4 loads, block-level combine, 1 atomic/block ----
__global__ __launch_bounds__(256) void minmax_kernel(const float4* __restrict__ d, unsigned* __restrict__ mm){
    unsigned lmin = 0xFFFFFFFFu, lmax = 0u;
    const int total4 = NB*HW/4;
    for (int i = blockIdx.x*256 + threadIdx.x; i < total4; i += gridDim.x*256){
        float4 v = d[i];
        unsigned e0 = fenc(v.x), e1 = fenc(v.y), e2 = fenc(v.z), e3 = fenc(v.w);
        lmin = min(lmin, min(min(e0,e1), min(e2,e3)));
        lmax = max(lmax, max(max(e0,e1), max(e2,e3)));
    }
    #pragma unroll
    for (int off = 32; off; off >>= 1){
        lmin = min(lmin, (unsigned)__shfl_down((int)lmin, off));
        lmax = max(lmax, (unsigned)__shfl_down((int)lmax, off));
    }
    __shared__ unsigned smin[4], smax[4];
    int wave = threadIdx.x >> 6, lane = threadIdx.x & 63;
    if (lane == 0){ smin[wave] = lmin; smax[wave] = lmax; }
    __syncthreads();
    if (threadIdx.x == 0){
        unsigned bmin = min(min(smin[0],smin[1]), min(smin[2],smin[3]));
        unsigned bmax = max(max(smax[0],smax[1]), max(smax[2],smax[3]));
        atomicMin(&mm[0], bmin);
        atomicMax(&mm[1], bmax);
    }
}

// ---- normal1 (interleaved x,y,z): sobel over vertex1, cross, normalize, mask; also weights=1 ----
__global__ __launch_bounds__(256) void normal_kernel(const float* __restrict__ depth1,
                                                     const float* __restrict__ Kp,
                                                     const unsigned* __restrict__ mm,
                                                     float* __restrict__ normal1,
                                                     float* __restrict__ weights){
    int b = blockIdx.y;
    int pix = blockIdx.x*256 + threadIdx.x;
    int r = pix / IMW, c = pix % IMW;
    const float fx = Kp[b*4+0], fy = Kp[b*4+1], cx = Kp[b*4+2], cy = Kp[b*4+3];
    const float inv_fx = 1.f/fx, inv_fy = 1.f/fy;
    const float* __restrict__ d = depth1 + (size_t)b*HW;
    int rm = max(r-1,0), rp = min(r+1,IMH-1), cm = max(c-1,0), cp = min(c+1,IMW-1);

    auto vert = [&](int rr, int cc, float v[3]){
        float dd = d[rr*IMW+cc];
        v[0] = ((float)cc - cx)*inv_fx*dd;
        v[1] = ((float)rr - cy)*inv_fy*dd;
        v[2] = dd;
    };
    float va[3],vb[3],vc2[3],vd[3],ve[3],vf[3],vg[3],vh[3];
    vert(rm,cm,va); vert(rm,c,vb);  vert(rm,cp,vc2);
    vert(r ,cm,vd);                 vert(r ,cp,ve);
    vert(rp,cm,vf); vert(rp,c,vg);  vert(rp,cp,vh);

    float dx[3], dy[3];
    #pragma unroll
    for (int k=0;k<3;k++){
        dx[k] = (vc2[k]-va[k]) + 2.f*(ve[k]-vd[k]) + (vh[k]-vf[k]);
        dy[k] = (vf[k]-va[k]) + 2.f*(vg[k]-vb[k]) + (vh[k]-vc2[k]);
    }
    float nx = dx[1]*dy[2] - dx[2]*dy[1];
    float ny = dx[2]*dy[0] - dx[0]*dy[2];
    float nz = dx[0]*dy[1] - dx[1]*dy[0];
    float mag = sqrtf(nx*nx + ny*ny + nz*nz + 1e-16f);
    float inv = __builtin_amdgcn_rcpf(mag + 1e-8f);
    nx *= inv; ny *= inv; nz *= inv;

    float dc = d[r*IMW+c];
    float dmin = fdec(mm[0]), dmax = fdec(mm[1]);
    if (dc == dmin || dc == dmax){ nx = 0.f; ny = 0.f; nz = 0.f; }

    size_t base = ((size_t)b*HW + pix)*3;
    normal1[base+0] = nx;
    normal1[base+1] = ny;
    normal1[base+2] = nz;
    weights[(size_t)b*HW + pix] = 1.f;
}

// ---- per-pixel ICP residual/Jacobian; 27 sums in registers over PPT pixels ----
__global__ __launch_bounds__(256) void iter_kernel(const float* __restrict__ depth0,
                                                   const float* __restrict__ depth1,
                                                   const float* __restrict__ normal1,
                                                   const float* __restrict__ Kp,
                                                   const float* __restrict__ stateR,
                                                   const float* __restrict__ statet,
                                                   float* __restrict__ acc){
    const int b = blockIdx.y;
    const float fx = Kp[b*4+0], fy = Kp[b*4+1], cx = Kp[b*4+2], cy = Kp[b*4+3];
    const float inv_fx = 1.f/fx, inv_fy = 1.f/fy;
    float Rm[9];
    #pragma unroll
    for (int i=0;i<9;i++) Rm[i] = stateR[b*9+i];
    float tv[3];
    #pragma unroll
    for (int i=0;i<3;i++) tv[i] = statet[b*3+i];

    const float* __restrict__ d0p = depth0 + (size_t)b*HW;
    const float* __restrict__ d1  = depth1 + (size_t)b*HW;
    const float* __restrict__ nbs = normal1 + (size_t)b*HW*3;

    float accv[27];
    #pragma unroll
    for (int i=0;i<27;i++) accv[i] = 0.f;

    const int tid = blockIdx.x*256 + threadIdx.x;
    // stride is an exact multiple of IMW: c constant, r steps by STRIDE_ROWS
    const int c  = tid % IMW;
    const int r0 = tid / IMW;
    const float px0 = ((float)c - cx)*inv_fx;          // loop-invariant
    float py = ((float)r0 - cy)*inv_fy;                // incremented
    const float py_step = (float)STRIDE_ROWS*inv_fy;

    int pix = tid;

    #pragma unroll 1
    for (int pp = 0; pp < PPT; pp++){
        float d0 = d0p[pix];
        float V0x = px0*d0;
        float V0y = py*d0;
        float V0z = d0;

        float X = Rm[0]*V0x + Rm[1]*V0y + Rm[2]*V0z + tv[0];
        float Y = Rm[3]*V0x + Rm[4]*V0y + Rm[5]*V0z + tv[1];
        float Z = Rm[6]*V0x + Rm[7]*V0y + Rm[8]*V0z + tv[2];
        float invZ = __builtin_amdgcn_rcpf(Z);
        float uu = X*invZ*fx + cx;
        float vv = Y*invZ*fy + cy;

        bool inview = (uu > 0.f) && (uu < (float)(IMW-1)) && (vv > 0.f) && (vv < (float)(IMH-1));

        float J0=0.f,J1=0.f,J2=0.f,J3=0.f,J4=0.f,J5=0.f,wres=0.f;
        if (inview){
            float u0f = floorf(uu), v0f = floorf(vv);
            int u0 = (int)u0f, v0 = (int)v0f;
            float wu = uu - u0f, wv = vv - v0f;
            float w00 = (1.f-wu)*(1.f-wv), w10 = wu*(1.f-wv), w01 = (1.f-wu)*wv, w11 = wu*wv;
            int i00 = v0*IMW + u0;

            float d00 = d1[i00], d10 = d1[i00+1], d01 = d1[i00+IMW], d11 = d1[i00+IMW+1];
            float pxa = (u0f - cx)*inv_fx, pxb = pxa + inv_fx;
            float pya = (v0f - cy)*inv_fy, pyb = pya + inv_fy;
            float a = w00*d00, bb = w10*d10, cc = w01*d01, ee = w11*d11;
            float rVz = (a + bb) + (cc + ee);
            float rVx = (a + cc)*pxa + (bb + ee)*pxb;
            float rVy = (a + bb)*pya + (cc + ee)*pyb;

            const float* __restrict__ n00 = nbs + (size_t)i00*3;
            const float* __restrict__ n01 = nbs + (size_t)(i00+IMW)*3;
            float n0x = w00*n00[0] + w10*n00[3] + w01*n01[0] + w11*n01[3];
            float n0y = w00*n00[1] + w10*n00[4] + w01*n01[1] + w11*n01[4];
            float n0z = w00*n00[2] + w10*n00[5] + w01*n01[2] + w11*n01[5];

            float dfx = X - rVx, dfy = Y - rVy, dfz = Z - rVz;
            float d2 = dfx*dfx + dfy*dfy + dfz*dfz + 1e-16f;
            if (d2 <= 0.01f){
                float res = n0x*dfx + n0y*dfy + n0z*dfz;
                // NtC = n^T R
                float N0 = n0x*Rm[0] + n0y*Rm[3] + n0z*Rm[6];
                float N1 = n0x*Rm[1] + n0y*Rm[4] + n0z*Rm[7];
                float N2 = n0x*Rm[2] + n0y*Rm[5] + n0z*Rm[8];
                // cross(NtC, P0)
                float c0 = N1*V0z - N2*V0y;
                float c1 = N2*V0x - N0*V0z;
                float c2 = N0*V0y - N1*V0x;
                float ndot = fabsf(N2);
                float dsh = d0 - 0.4f;
                float sigz = 0.0012f + 0.0019f*dsh*dsh;
                float sigma = ndot*sigz + 0.001f;
                float invs = __builtin_amdgcn_rcpf(sigma + 1e-8f);
                wres = res*invs;
                J0 = -c0*invs; J1 = -c1*invs; J2 = -c2*invs;
                J3 =  N0*invs; J4 =  N1*invs; J5 =  N2*invs;
            }
        }

        float Jv[6] = {J0,J1,J2,J3,J4,J5};
        int idx = 0;
        #pragma unroll
        for (int k=0;k<6;k++)
            #pragma unroll
            for (int l=k;l<6;l++){ accv[idx] += Jv[k]*Jv[l]; idx++; }
        #pragma unroll
        for (int k=0;k<6;k++){ accv[idx] += Jv[k]*wres; idx++; }

        pix += STRIDE_PX;
        py  += py_step;
    }

    // one wave-level reduction per thread (amortized over PPT pixels)
    #pragma unroll
    for (int i=0;i<27;i++){
        float v = accv[i];
        #pragma unroll
        for (int off=32; off; off >>= 1) v += __shfl_down(v, off);
        accv[i] = v;
    }

    __shared__ float sacc[4][27];
    int wave = threadIdx.x >> 6, lane = threadIdx.x & 63;
    if (lane == 0){
        #pragma unroll
        for (int i=0;i<27;i++) sacc[wave][i] = accv[i];
    }
    __syncthreads();
    if (threadIdx.x < 27){
        float s = sacc[0][threadIdx.x] + sacc[1][threadIdx.x]
                + sacc[2][threadIdx.x] + sacc[3][threadIdx.x];
        atomicAdd(&acc[b*27 + threadIdx.x], s);
    }
}

// ---- per-batch 6x6 solve + twist update ----
__global__ void solve_kernel(float* __restrict__ acc,
                             float* __restrict__ stateR, float* __restrict__ statet,
                             float* __restrict__ outR, float* __restrict__ outt){
    int b = threadIdx.x;
    if (b >= NB) return;

    float a27[27];
    for (int i=0;i<27;i++) a27[i] = acc[b*27+i];
    // zero for next iteration
    for (int i=0;i<27;i++) acc[b*27+i] = 0.f;

    double A[6][6], rhs[6];
    int idx = 0;
    for (int k=0;k<6;k++)
        for (int l=k;l<6;l++){ A[k][l] = a27[idx]; A[l][k] = a27[idx]; idx++; }
    for (int k=0;k<6;k++) rhs[k] = a27[21+k];

    double tr = 0.0;
    for (int k=0;k<6;k++) tr += A[k][k];
    double lm = tr*1e-6;
    for (int k=0;k<6;k++) A[k][k] += lm;

    // Gauss-Jordan with partial pivoting: M = [A | rhs]
    double M[6][7];
    for (int i=0;i<6;i++){ for (int j=0;j<6;j++) M[i][j]=A[i][j]; M[i][6]=rhs[i]; }
    for (int col=0; col<6; col++){
        int piv = col; double best = fabs(M[col][col]);
        for (int r2=col+1; r2<6; r2++){
            double v = fabs(M[r2][col]);
            if (v > best){ best = v; piv = r2; }
        }
        if (piv != col)
            for (int j=0;j<7;j++){ double tmp = M[col][j]; M[col][j] = M[piv][j]; M[piv][j] = tmp; }
        double p = M[col][col];
        for (int j=col;j<7;j++) M[col][j] /= p;
        for (int r2=0;r2<6;r2++){
            if (r2 == col) continue;
            double f = M[r2][col];
            for (int j=col;j<7;j++) M[r2][j] -= f*M[col][j];
        }
    }
    double xi[6];
    for (int k=0;k<6;k++) xi[k] = M[k][6];

    // dR = twist2mat(-xi[:3])
    double w0 = -xi[0], w1 = -xi[1], w2 = -xi[2];
    double th = sqrt(w0*w0 + w1*w1 + w2*w2 + 1e-24);
    double kx = w0/th, ky = w1/th, kz = w2/th;
    double s = sin(th), cm1 = 1.0 - cos(th);
    double Kv[3][3] = {{0,-kz,ky},{kz,0,-kx},{-ky,kx,0}};
    double K2[3][3];
    for (int i=0;i<3;i++)
        for (int j=0;j<3;j++){
            double acc2 = 0.0;
            for (int k=0;k<3;k++) acc2 += Kv[i][k]*Kv[k][j];
            K2[i][j] = acc2;
        }
    double dR[3][3];
    for (int i=0;i<3;i++)
        for (int j=0;j<3;j++)
            dR[i][j] = (i==j ? 1.0 : 0.0) + s*Kv[i][j] + cm1*K2[i][j];
    double dt[3];
    for (int i=0;i<3;i++)
        dt[i] = -(dR[i][0]*xi[3] + dR[i][1]*xi[4] + dR[i][2]*xi[5]);

    // R_new = R_old @ dR; t_new = R_old @ dt + t_old
    double Ro[3][3];
    for (int i=0;i<3;i++) for (int j=0;j<3;j++) Ro[i][j] = (double)stateR[b*9 + i*3 + j];
    double to[3];
    for (int i=0;i<3;i++) to[i] = (double)statet[b*3+i];

    double Rn[3][3], tn[3];
    for (int i=0;i<3;i++)
        for (int j=0;j<3;j++){
            double acc2 = 0.0;
            for (int k=0;k<3;k++) acc2 += Ro[i][k]*dR[k][j];
            Rn[i][j] = acc2;
        }
    for (int i=0;i<3;i++)
        tn[i] = Ro[i][0]*dt[0] + Ro[i][1]*dt[1] + Ro[i][2]*dt[2] + to[i];

    for (int i=0;i<3;i++)
        for (int j=0;j<3;j++){
            float v = (float)Rn[i][j];
            stateR[b*9 + i*3 + j] = v;
            outR[b*9 + i*3 + j] = v;
        }
    for (int i=0;i<3;i++){
        float v = (float)tn[i];
        statet[b*3+i] = v;
        outt[b*3+i] = v;
    }
}

extern "C" void kernel_launch(void* const* d_in, const int* in_sizes, int n_in,
                              void* d_out, int out_size, void* d_ws, size_t ws_size,
                              hipStream_t stream){
    const float* depth0 = (const float*)d_in[0];
    const float* depth1 = (const float*)d_in[1];
    const float* Kp     = (const float*)d_in[2];
    const float* Rin    = (const float*)d_in[3];
    const float* tin    = (const float*)d_in[4];

    float* out     = (float*)d_out;
    float* outR    = out;
    float* outt    = out + NB*9;
    float* weights = out + NB*12;

    float* normal1 = (float*)d_ws;                        // 3*NB*HW floats interleaved (~59 MB)
    float* stateR  = normal1 + (size_t)3*NB*HW;           // NB*9
    float* statet  = stateR + NB*9;                       // NB*3
    unsigned* mm   = (unsigned*)(statet + NB*3);          // 2
    float* acc     = (float*)(mm + 2);                    // NB*27

    init_kernel<<<1, 256, 0, stream>>>(Rin, tin, stateR, statet, mm, acc);
    minmax_kernel<<<dim3(256), 256, 0, stream>>>((const float4*)depth1, mm);
    normal_kernel<<<dim3(HW/256, NB), 256, 0, stream>>>(depth1, Kp, mm, normal1, weights);
    for (int it = 0; it < 3; it++){
        iter_kernel<<<dim3(BPB, NB), 256, 0, stream>>>(depth0, depth1, normal1, Kp, stateR, statet, acc);
        solve_kernel<<<1, 64, 0, stream>>>(acc, stateR, statet, outR, outt);
    }
}

// Round 5
// 251.931 us; speedup vs baseline: 3.0841x; 1.0854x over previous
//
#include <hip/hip_runtime.h>
#include <hip/hip_fp16.h>

#define IMH 480
#define IMW 640
#define HW (IMH*IMW)
#define NB 16

// iter_kernel geometry: 100 blocks/batch * 256 thr * 4 px * 3 groups == HW
#define BPB 100
#define TPX 4
#define GROUPS 3
#define THREADS_PB (BPB*256)          // 25600 threads per batch
#define GSTRIDE (THREADS_PB*TPX)      // 102400 px per group = 160 rows
#define GROWS (GSTRIDE/IMW)           // 160

// ---- order-preserving float<->uint encoding (for atomic min/max) ----
__device__ inline unsigned fenc(float x){
    unsigned u = __float_as_uint(x);
    return (u & 0x80000000u) ? ~u : (u | 0x80000000u);
}
__device__ inline float fdec(unsigned e){
    unsigned u = (e & 0x80000000u) ? (e & 0x7FFFFFFFu) : ~e;
    return __uint_as_float(u);
}

// ---- init: copy R,t to state, zero accumulators, init min/max ----
__global__ void init_kernel(const float* __restrict__ Rin, const float* __restrict__ tin,
                            float* __restrict__ stateR, float* __restrict__ statet,
                            unsigned* __restrict__ mm, float* __restrict__ acc){
    int i = threadIdx.x;
    if (i < NB*9) stateR[i] = Rin[i];
    if (i < NB*3) statet[i] = tin[i];
    if (i == 0){ mm[0] = 0xFFFFFFFFu; mm[1] = 0u; }
    for (int k = i; k < NB*27; k += 256) acc[k] = 0.f;
}

// ---- global min/max of depth1: float4 loads, block-level combine, 1 atomic/block ----
__global__ __launch_bounds__(256) void minmax_kernel(const float4* __restrict__ d, unsigned* __restrict__ mm){
    unsigned lmin = 0xFFFFFFFFu, lmax = 0u;
    const int total4 = NB*HW/4;
    for (int i = blockIdx.x*256 + threadIdx.x; i < total4; i += gridDim.x*256){
        float4 v = d[i];
        unsigned e0 = fenc(v.x), e1 = fenc(v.y), e2 = fenc(v.z), e3 = fenc(v.w);
        lmin = min(lmin, min(min(e0,e1), min(e2,e3)));
        lmax = max(lmax, max(max(e0,e1), max(e2,e3)));
    }
    #pragma unroll
    for (int off = 32; off; off >>= 1){
        lmin = min(lmin, (unsigned)__shfl_down((int)lmin, off));
        lmax = max(lmax, (unsigned)__shfl_down((int)lmax, off));
    }
    __shared__ unsigned smin[4], smax[4];
    int wave = threadIdx.x >> 6, lane = threadIdx.x & 63;
    if (lane == 0){ smin[wave] = lmin; smax[wave] = lmax; }
    __syncthreads();
    if (threadIdx.x == 0){
        unsigned bmin = min(min(smin[0],smin[1]), min(smin[2],smin[3]));
        unsigned bmax = max(max(smax[0],smax[1]), max(smax[2],smax[3]));
        atomicMin(&mm[0], bmin);
        atomicMax(&mm[1], bmax);
    }
}

// ---- normal1 packed half4 (x,y,z,0 as uint2): sobel, cross, normalize, mask; weights=1 ----
__global__ __launch_bounds__(256) void normal_kernel(const float* __restrict__ depth1,
                                                     const float* __restrict__ Kp,
                                                     const unsigned* __restrict__ mm,
                                                     uint2* __restrict__ nrm,
                                                     float* __restrict__ weights){
    int b = blockIdx.y;
    int pix = blockIdx.x*256 + threadIdx.x;
    int r = pix / IMW, c = pix % IMW;
    const float fx = Kp[b*4+0], fy = Kp[b*4+1], cx = Kp[b*4+2], cy = Kp[b*4+3];
    const float inv_fx = 1.f/fx, inv_fy = 1.f/fy;
    const float* __restrict__ d = depth1 + (size_t)b*HW;
    int rm = max(r-1,0), rp = min(r+1,IMH-1), cm = max(c-1,0), cp = min(c+1,IMW-1);

    auto vert = [&](int rr, int cc, float v[3]){
        float dd = d[rr*IMW+cc];
        v[0] = ((float)cc - cx)*inv_fx*dd;
        v[1] = ((float)rr - cy)*inv_fy*dd;
        v[2] = dd;
    };
    float va[3],vb[3],vc2[3],vd[3],ve[3],vf[3],vg[3],vh[3];
    vert(rm,cm,va); vert(rm,c,vb);  vert(rm,cp,vc2);
    vert(r ,cm,vd);                 vert(r ,cp,ve);
    vert(rp,cm,vf); vert(rp,c,vg);  vert(rp,cp,vh);

    float dx[3], dy[3];
    #pragma unroll
    for (int k=0;k<3;k++){
        dx[k] = (vc2[k]-va[k]) + 2.f*(ve[k]-vd[k]) + (vh[k]-vf[k]);
        dy[k] = (vf[k]-va[k]) + 2.f*(vg[k]-vb[k]) + (vh[k]-vc2[k]);
    }
    float nx = dx[1]*dy[2] - dx[2]*dy[1];
    float ny = dx[2]*dy[0] - dx[0]*dy[2];
    float nz = dx[0]*dy[1] - dx[1]*dy[0];
    float mag = sqrtf(nx*nx + ny*ny + nz*nz + 1e-16f);
    float inv = __builtin_amdgcn_rcpf(mag + 1e-8f);
    nx *= inv; ny *= inv; nz *= inv;

    float dc = d[r*IMW+c];
    float dmin = fdec(mm[0]), dmax = fdec(mm[1]);
    if (dc == dmin || dc == dmax){ nx = 0.f; ny = 0.f; nz = 0.f; }

    __half2 hxy = __floats2half2_rn(nx, ny);
    __half2 hz0 = __floats2half2_rn(nz, 0.f);
    uint2 p;
    p.x = *reinterpret_cast<unsigned*>(&hxy);
    p.y = *reinterpret_cast<unsigned*>(&hz0);
    nrm[(size_t)b*HW + pix] = p;
    weights[(size_t)b*HW + pix] = 1.f;
}

// ---- per-pixel ICP residual/Jacobian; 4-px groups for ILP; 27 sums in registers ----
__global__ __launch_bounds__(256) void iter_kernel(const float4* __restrict__ depth0_v4,
                                                   const float* __restrict__ depth1,
                                                   const uint2* __restrict__ nrm,
                                                   const float* __restrict__ Kp,
                                                   const float* __restrict__ stateR,
                                                   const float* __restrict__ statet,
                                                   float* __restrict__ acc){
    const int b = blockIdx.y;
    const float fx = Kp[b*4+0], fy = Kp[b*4+1], cx = Kp[b*4+2], cy = Kp[b*4+3];
    const float inv_fx = 1.f/fx, inv_fy = 1.f/fy;
    float Rm[9];
    #pragma unroll
    for (int i=0;i<9;i++) Rm[i] = stateR[b*9+i];
    float tv[3];
    #pragma unroll
    for (int i=0;i<3;i++) tv[i] = statet[b*3+i];

    const float4* __restrict__ d0v = depth0_v4 + (size_t)b*(HW/4);
    const float* __restrict__ d1   = depth1 + (size_t)b*HW;
    const uint2* __restrict__ nb_  = nrm + (size_t)b*HW;

    float accv[27];
    #pragma unroll
    for (int i=0;i<27;i++) accv[i] = 0.f;

    const int tid = blockIdx.x*256 + threadIdx.x;     // 0..25599
    const int base0 = tid*TPX;
    const int c0 = base0 % IMW;                        // same row for all 4 px (640%4==0)
    const int r0 = base0 / IMW;
    const float px_base = ((float)c0 - cx)*inv_fx;     // px for j advances by inv_fx
    float pyv = ((float)r0 - cy)*inv_fy;
    const float py_step = (float)GROWS*inv_fy;

    #pragma unroll 1
    for (int g = 0; g < GROUPS; g++){
        float4 d4 = d0v[tid + g*THREADS_PB];
        float dd[4] = {d4.x, d4.y, d4.z, d4.w};

        #pragma unroll
        for (int j = 0; j < TPX; j++){
            float d0 = dd[j];
            float V0x = (px_base + (float)j*inv_fx)*d0;
            float V0y = pyv*d0;
            float V0z = d0;

            float X = Rm[0]*V0x + Rm[1]*V0y + Rm[2]*V0z + tv[0];
            float Y = Rm[3]*V0x + Rm[4]*V0y + Rm[5]*V0z + tv[1];
            float Z = Rm[6]*V0x + Rm[7]*V0y + Rm[8]*V0z + tv[2];
            float invZ = __builtin_amdgcn_rcpf(Z);
            float uu = X*invZ*fx + cx;
            float vv = Y*invZ*fy + cy;

            bool inview = (uu > 0.f) && (uu < (float)(IMW-1)) && (vv > 0.f) && (vv < (float)(IMH-1));

            float J0=0.f,J1=0.f,J2=0.f,J3=0.f,J4=0.f,J5=0.f,wres=0.f;
            if (inview){
                float u0f = floorf(uu), v0f = floorf(vv);
                int u0 = (int)u0f, v0 = (int)v0f;
                float wu = uu - u0f, wv = vv - v0f;
                float w00 = (1.f-wu)*(1.f-wv), w10 = wu*(1.f-wv), w01 = (1.f-wu)*wv, w11 = wu*wv;
                int i00 = v0*IMW + u0;

                float d00 = d1[i00], d10 = d1[i00+1], d01 = d1[i00+IMW], d11 = d1[i00+IMW+1];
                uint2 h00 = nb_[i00], h10 = nb_[i00+1], h01 = nb_[i00+IMW], h11 = nb_[i00+IMW+1];

                float pxa = (u0f - cx)*inv_fx, pxb = pxa + inv_fx;
                float pya = (v0f - cy)*inv_fy, pyb = pya + inv_fy;
                float a = w00*d00, bb = w10*d10, cc = w01*d01, ee = w11*d11;
                float rVz = (a + bb) + (cc + ee);
                float rVx = (a + cc)*pxa + (bb + ee)*pxb;
                float rVy = (a + bb)*pya + (cc + ee)*pyb;

                float2 n00xy = __half22float2(*reinterpret_cast<__half2*>(&h00.x));
                float2 n00z_ = __half22float2(*reinterpret_cast<__half2*>(&h00.y));
                float2 n10xy = __half22float2(*reinterpret_cast<__half2*>(&h10.x));
                float2 n10z_ = __half22float2(*reinterpret_cast<__half2*>(&h10.y));
                float2 n01xy = __half22float2(*reinterpret_cast<__half2*>(&h01.x));
                float2 n01z_ = __half22float2(*reinterpret_cast<__half2*>(&h01.y));
                float2 n11xy = __half22float2(*reinterpret_cast<__half2*>(&h11.x));
                float2 n11z_ = __half22float2(*reinterpret_cast<__half2*>(&h11.y));

                float n0x = w00*n00xy.x + w10*n10xy.x + w01*n01xy.x + w11*n11xy.x;
                float n0y = w00*n00xy.y + w10*n10xy.y + w01*n01xy.y + w11*n11xy.y;
                float n0z = w00*n00z_.x + w10*n10z_.x + w01*n01z_.x + w11*n11z_.x;

                float dfx = X - rVx, dfy = Y - rVy, dfz = Z - rVz;
                float d2 = dfx*dfx + dfy*dfy + dfz*dfz + 1e-16f;
                if (d2 <= 0.01f){
                    float res = n0x*dfx + n0y*dfy + n0z*dfz;
                    float N0 = n0x*Rm[0] + n0y*Rm[3] + n0z*Rm[6];
                    float N1 = n0x*Rm[1] + n0y*Rm[4] + n0z*Rm[7];
                    float N2 = n0x*Rm[2] + n0y*Rm[5] + n0z*Rm[8];
                    float cr0 = N1*V0z - N2*V0y;
                    float cr1 = N2*V0x - N0*V0z;
                    float cr2 = N0*V0y - N1*V0x;
                    float ndot = fabsf(N2);
                    float dsh = d0 - 0.4f;
                    float sigz = 0.0012f + 0.0019f*dsh*dsh;
                    float sigma = ndot*sigz + 0.001f;
                    float invs = __builtin_amdgcn_rcpf(sigma + 1e-8f);
                    wres = res*invs;
                    J0 = -cr0*invs; J1 = -cr1*invs; J2 = -cr2*invs;
                    J3 =  N0*invs;  J4 =  N1*invs;  J5 =  N2*invs;
                }
            }

            float Jv[6] = {J0,J1,J2,J3,J4,J5};
            int idx = 0;
            #pragma unroll
            for (int k=0;k<6;k++)
                #pragma unroll
                for (int l=k;l<6;l++){ accv[idx] += Jv[k]*Jv[l]; idx++; }
            #pragma unroll
            for (int k=0;k<6;k++){ accv[idx] += Jv[k]*wres; idx++; }
        }

        pyv += py_step;
    }

    // one wave-level reduction per thread (amortized over 12 pixels)
    #pragma unroll
    for (int i=0;i<27;i++){
        float v = accv[i];
        #pragma unroll
        for (int off=32; off; off >>= 1) v += __shfl_down(v, off);
        accv[i] = v;
    }

    __shared__ float sacc[4][27];
    int wave = threadIdx.x >> 6, lane = threadIdx.x & 63;
    if (lane == 0){
        #pragma unroll
        for (int i=0;i<27;i++) sacc[wave][i] = accv[i];
    }
    __syncthreads();
    if (threadIdx.x < 27){
        float s = sacc[0][threadIdx.x] + sacc[1][threadIdx.x]
                + sacc[2][threadIdx.x] + sacc[3][threadIdx.x];
        atomicAdd(&acc[b*27 + threadIdx.x], s);
    }
}

// ---- per-batch 6x6 solve + twist update ----
__global__ void solve_kernel(float* __restrict__ acc,
                             float* __restrict__ stateR, float* __restrict__ statet,
                             float* __restrict__ outR, float* __restrict__ outt){
    int b = threadIdx.x;
    if (b >= NB) return;

    float a27[27];
    for (int i=0;i<27;i++) a27[i] = acc[b*27+i];
    for (int i=0;i<27;i++) acc[b*27+i] = 0.f;

    double A[6][6], rhs[6];
    int idx = 0;
    for (int k=0;k<6;k++)
        for (int l=k;l<6;l++){ A[k][l] = a27[idx]; A[l][k] = a27[idx]; idx++; }
    for (int k=0;k<6;k++) rhs[k] = a27[21+k];

    double tr = 0.0;
    for (int k=0;k<6;k++) tr += A[k][k];
    double lm = tr*1e-6;
    for (int k=0;k<6;k++) A[k][k] += lm;

    double M[6][7];
    for (int i=0;i<6;i++){ for (int j=0;j<6;j++) M[i][j]=A[i][j]; M[i][6]=rhs[i]; }
    for (int col=0; col<6; col++){
        int piv = col; double best = fabs(M[col][col]);
        for (int r2=col+1; r2<6; r2++){
            double v = fabs(M[r2][col]);
            if (v > best){ best = v; piv = r2; }
        }
        if (piv != col)
            for (int j=0;j<7;j++){ double tmp = M[col][j]; M[col][j] = M[piv][j]; M[piv][j] = tmp; }
        double p = M[col][col];
        for (int j=col;j<7;j++) M[col][j] /= p;
        for (int r2=0;r2<6;r2++){
            if (r2 == col) continue;
            double f = M[r2][col];
            for (int j=col;j<7;j++) M[r2][j] -= f*M[col][j];
        }
    }
    double xi[6];
    for (int k=0;k<6;k++) xi[k] = M[k][6];

    double w0 = -xi[0], w1 = -xi[1], w2 = -xi[2];
    double th = sqrt(w0*w0 + w1*w1 + w2*w2 + 1e-24);
    double kx = w0/th, ky = w1/th, kz = w2/th;
    double s = sin(th), cm1 = 1.0 - cos(th);
    double Kv[3][3] = {{0,-kz,ky},{kz,0,-kx},{-ky,kx,0}};
    double K2[3][3];
    for (int i=0;i<3;i++)
        for (int j=0;j<3;j++){
            double acc2 = 0.0;
            for (int k=0;k<3;k++) acc2 += Kv[i][k]*Kv[k][j];
            K2[i][j] = acc2;
        }
    double dR[3][3];
    for (int i=0;i<3;i++)
        for (int j=0;j<3;j++)
            dR[i][j] = (i==j ? 1.0 : 0.0) + s*Kv[i][j] + cm1*K2[i][j];
    double dt[3];
    for (int i=0;i<3;i++)
        dt[i] = -(dR[i][0]*xi[3] + dR[i][1]*xi[4] + dR[i][2]*xi[5]);

    double Ro[3][3];
    for (int i=0;i<3;i++) for (int j=0;j<3;j++) Ro[i][j] = (double)stateR[b*9 + i*3 + j];
    double to[3];
    for (int i=0;i<3;i++) to[i] = (double)statet[b*3+i];

    double Rn[3][3], tn[3];
    for (int i=0;i<3;i++)
        for (int j=0;j<3;j++){
            double acc2 = 0.0;
            for (int k=0;k<3;k++) acc2 += Ro[i][k]*dR[k][j];
            Rn[i][j] = acc2;
        }
    for (int i=0;i<3;i++)
        tn[i] = Ro[i][0]*dt[0] + Ro[i][1]*dt[1] + Ro[i][2]*dt[2] + to[i];

    for (int i=0;i<3;i++)
        for (int j=0;j<3;j++){
            float v = (float)Rn[i][j];
            stateR[b*9 + i*3 + j] = v;
            outR[b*9 + i*3 + j] = v;
        }
    for (int i=0;i<3;i++){
        float v = (float)tn[i];
        statet[b*3+i] = v;
        outt[b*3+i] = v;
    }
}

extern "C" void kernel_launch(void* const* d_in, const int* in_sizes, int n_in,
                              void* d_out, int out_size, void* d_ws, size_t ws_size,
                              hipStream_t stream){
    const float* depth0 = (const float*)d_in[0];
    const float* depth1 = (const float*)d_in[1];
    const float* Kp     = (const float*)d_in[2];
    const float* Rin    = (const float*)d_in[3];
    const float* tin    = (const float*)d_in[4];

    float* out     = (float*)d_out;
    float* outR    = out;
    float* outt    = out + NB*9;
    float* weights = out + NB*12;

    uint2* nrm     = (uint2*)d_ws;                        // NB*HW uint2 (~39 MB)
    float* stateR  = (float*)(nrm + (size_t)NB*HW);       // NB*9
    float* statet  = stateR + NB*9;                       // NB*3
    unsigned* mm   = (unsigned*)(statet + NB*3);          // 2
    float* acc     = (float*)(mm + 2);                    // NB*27

    init_kernel<<<1, 256, 0, stream>>>(Rin, tin, stateR, statet, mm, acc);
    minmax_kernel<<<dim3(256), 256, 0, stream>>>((const float4*)depth1, mm);
    normal_kernel<<<dim3(HW/256, NB), 256, 0, stream>>>(depth1, Kp, mm, nrm, weights);
    for (int it = 0; it < 3; it++){
        iter_kernel<<<dim3(BPB, NB), 256, 0, stream>>>((const float4*)depth0, depth1, nrm, Kp, stateR, statet, acc);
        solve_kernel<<<1, 64, 0, stream>>>(acc, stateR, statet, outR, outt);
    }
}